// Round 1
// baseline (64.347 us; speedup 1.0000x reference)
//
#include <hip/hip_runtime.h>
#include <math.h>

#ifndef __has_builtin
#define __has_builtin(x) 0
#endif
#if __has_builtin(__builtin_amdgcn_exp2f)
#define EXP2F(x) __builtin_amdgcn_exp2f(x)
#else
#define EXP2F(x) exp2f(x)
#endif

namespace {

constexpr int K_GRID = 10000;          // grid points
constexpr int K_PAD  = 10240;          // 160 * 64, padded for even lane strides
constexpr int DIM    = 512;            // out_features
constexpr int NBATCH = 8192;           // batch
constexpr int NPW    = 8;              // samples per wave
constexpr int WPB    = 4;              // waves per block
constexpr int BLOCK  = WPB * 64;
constexpr float LOG2E = 1.4426950408889634f;

// table[k] = { R_k = -(beta/2)*log2e*||yg_k||^2 , g0_k , g1_k , 0 }
__global__ void build_table_kernel(const float* __restrict__ W,
                                   const float* __restrict__ b,
                                   const float* __restrict__ betta,
                                   const float* __restrict__ grid,
                                   float4* __restrict__ table) {
    int k = blockIdx.x * blockDim.x + threadIdx.x;
    if (k >= K_PAD) return;
    if (k >= K_GRID) {              // padding: exp2 -> 0, weights 0
        table[k] = make_float4(-1e30f, 0.0f, 0.0f, 0.0f);
        return;
    }
    const float g0 = grid[2 * k + 0];
    const float g1 = grid[2 * k + 1];
    const float beta = betta[0];
    const float2* Wv = reinterpret_cast<const float2*>(W);  // {W[d][0], W[d][1]}
    float ss0 = 0.0f, ss1 = 0.0f;
    #pragma unroll 8
    for (int d = 0; d < DIM; d += 2) {
        float2 wa = Wv[d];
        float2 wb = Wv[d + 1];
        float ya = fmaf(g0, wa.x, fmaf(g1, wa.y, b[d]));
        float yb = fmaf(g0, wb.x, fmaf(g1, wb.y, b[d + 1]));
        ss0 = fmaf(ya, ya, ss0);
        ss1 = fmaf(yb, yb, ss1);
    }
    float R = -0.5f * beta * LOG2E * (ss0 + ss1);
    table[k] = make_float4(R, g0, g1, 0.0f);
}

// Each wave handles NPW samples: computes A,C dots, then 2-pass softmax over the table.
__global__ __launch_bounds__(BLOCK) void gtm_main_kernel(
        const float* __restrict__ X,
        const float* __restrict__ W,
        const float* __restrict__ betta,
        const float4* __restrict__ table,
        float* __restrict__ out) {
    const int lane = threadIdx.x & 63;
    const int wave = threadIdx.x >> 6;
    const int nbase = (blockIdx.x * WPB + wave) * NPW;
    const float beta = betta[0];

    // per-lane W fragment: d = lane*8 + j, j = 0..7
    float w0[8], w1[8];
    {
        const float4* Wv = reinterpret_cast<const float4*>(W);
        const int base = lane * 4;  // float4 index: covers d pairs
        #pragma unroll
        for (int j = 0; j < 4; ++j) {
            float4 wv = Wv[base + j];
            w0[2 * j + 0] = wv.x; w1[2 * j + 0] = wv.y;
            w0[2 * j + 1] = wv.z; w1[2 * j + 1] = wv.w;
        }
    }

    const float scaleAC = beta * LOG2E;
    float A[NPW], C[NPW];
    #pragma unroll
    for (int nn = 0; nn < NPW; ++nn) {
        const int n = nbase + nn;
        const float4* Xv = reinterpret_cast<const float4*>(X + (size_t)n * DIM);
        float4 xa = Xv[lane * 2 + 0];
        float4 xb = Xv[lane * 2 + 1];
        float pa = 0.0f, pc = 0.0f;
        pa = fmaf(w0[0], xa.x, pa); pc = fmaf(w1[0], xa.x, pc);
        pa = fmaf(w0[1], xa.y, pa); pc = fmaf(w1[1], xa.y, pc);
        pa = fmaf(w0[2], xa.z, pa); pc = fmaf(w1[2], xa.z, pc);
        pa = fmaf(w0[3], xa.w, pa); pc = fmaf(w1[3], xa.w, pc);
        pa = fmaf(w0[4], xb.x, pa); pc = fmaf(w1[4], xb.x, pc);
        pa = fmaf(w0[5], xb.y, pa); pc = fmaf(w1[5], xb.y, pc);
        pa = fmaf(w0[6], xb.z, pa); pc = fmaf(w1[6], xb.z, pc);
        pa = fmaf(w0[7], xb.w, pa); pc = fmaf(w1[7], xb.w, pc);
        #pragma unroll
        for (int off = 32; off > 0; off >>= 1) {
            pa += __shfl_xor(pa, off, 64);
            pc += __shfl_xor(pc, off, 64);
        }
        A[nn] = scaleAC * pa;
        C[nn] = scaleAC * pc;
    }

    constexpr int NIT = K_PAD / 64;  // 160

    // ---- pass 1: exact max of s_k = R + g0*A + g1*C over k ----
    float m[NPW];
    #pragma unroll
    for (int nn = 0; nn < NPW; ++nn) m[nn] = -3.0e38f;

    for (int it = 0; it < NIT; it += 4) {
        float4 t0 = table[(it + 0) * 64 + lane];
        float4 t1 = table[(it + 1) * 64 + lane];
        float4 t2 = table[(it + 2) * 64 + lane];
        float4 t3 = table[(it + 3) * 64 + lane];
        #pragma unroll
        for (int nn = 0; nn < NPW; ++nn) {
            float s0 = fmaf(t0.y, A[nn], fmaf(t0.z, C[nn], t0.x));
            float s1 = fmaf(t1.y, A[nn], fmaf(t1.z, C[nn], t1.x));
            float s2 = fmaf(t2.y, A[nn], fmaf(t2.z, C[nn], t2.x));
            float s3 = fmaf(t3.y, A[nn], fmaf(t3.z, C[nn], t3.x));
            m[nn] = fmaxf(m[nn], fmaxf(fmaxf(s0, s1), fmaxf(s2, s3)));
        }
    }
    #pragma unroll
    for (int nn = 0; nn < NPW; ++nn) {
        float mv = m[nn];
        #pragma unroll
        for (int off = 32; off > 0; off >>= 1)
            mv = fmaxf(mv, __shfl_xor(mv, off, 64));
        m[nn] = mv;
    }

    // ---- pass 2: sum exp2(s - m), and weighted g0/g1 sums ----
    float wsum[NPW], wa0[NPW], wa1[NPW];
    #pragma unroll
    for (int nn = 0; nn < NPW; ++nn) { wsum[nn] = 0.0f; wa0[nn] = 0.0f; wa1[nn] = 0.0f; }

    for (int it = 0; it < NIT; it += 4) {
        float4 t0 = table[(it + 0) * 64 + lane];
        float4 t1 = table[(it + 1) * 64 + lane];
        float4 t2 = table[(it + 2) * 64 + lane];
        float4 t3 = table[(it + 3) * 64 + lane];
        #pragma unroll
        for (int nn = 0; nn < NPW; ++nn) {
            float s0 = fmaf(t0.y, A[nn], fmaf(t0.z, C[nn], t0.x));
            float s1 = fmaf(t1.y, A[nn], fmaf(t1.z, C[nn], t1.x));
            float s2 = fmaf(t2.y, A[nn], fmaf(t2.z, C[nn], t2.x));
            float s3 = fmaf(t3.y, A[nn], fmaf(t3.z, C[nn], t3.x));
            float e0 = EXP2F(s0 - m[nn]);
            float e1 = EXP2F(s1 - m[nn]);
            float e2 = EXP2F(s2 - m[nn]);
            float e3 = EXP2F(s3 - m[nn]);
            wsum[nn] += (e0 + e1) + (e2 + e3);
            wa0[nn] = fmaf(e0, t0.y, wa0[nn]);
            wa0[nn] = fmaf(e1, t1.y, wa0[nn]);
            wa0[nn] = fmaf(e2, t2.y, wa0[nn]);
            wa0[nn] = fmaf(e3, t3.y, wa0[nn]);
            wa1[nn] = fmaf(e0, t0.z, wa1[nn]);
            wa1[nn] = fmaf(e1, t1.z, wa1[nn]);
            wa1[nn] = fmaf(e2, t2.z, wa1[nn]);
            wa1[nn] = fmaf(e3, t3.z, wa1[nn]);
        }
    }

    #pragma unroll
    for (int nn = 0; nn < NPW; ++nn) {
        float sv = wsum[nn], v0 = wa0[nn], v1 = wa1[nn];
        #pragma unroll
        for (int off = 32; off > 0; off >>= 1) {
            sv += __shfl_xor(sv, off, 64);
            v0 += __shfl_xor(v0, off, 64);
            v1 += __shfl_xor(v1, off, 64);
        }
        if (lane == 0) {
            const int n = nbase + nn;
            float inv = 1.0f / sv;
            reinterpret_cast<float2*>(out)[n] = make_float2(v0 * inv, v1 * inv);
        }
    }
}

}  // namespace

extern "C" void kernel_launch(void* const* d_in, const int* in_sizes, int n_in,
                              void* d_out, int out_size, void* d_ws, size_t ws_size,
                              hipStream_t stream) {
    const float* X     = (const float*)d_in[0];  // [8192, 512]
    const float* W     = (const float*)d_in[1];  // [512, 2]
    const float* b     = (const float*)d_in[2];  // [512]
    const float* betta = (const float*)d_in[3];  // [1]
    const float* grid  = (const float*)d_in[4];  // [10000, 2]
    float* out = (float*)d_out;                  // [8192, 2]
    float4* table = (float4*)d_ws;               // K_PAD * 16 bytes = 160 KiB

    build_table_kernel<<<K_PAD / 256, 256, 0, stream>>>(W, b, betta, grid, table);

    const int blocks = NBATCH / (WPB * NPW);     // 256
    gtm_main_kernel<<<blocks, BLOCK, 0, stream>>>(X, W, betta, table, out);
}

// Round 2
// 42.502 us; speedup vs baseline: 1.5140x; 1.5140x over previous
//
#include <hip/hip_runtime.h>
#include <math.h>

#ifndef __has_builtin
#define __has_builtin(x) 0
#endif
#if __has_builtin(__builtin_amdgcn_exp2f)
#define EXP2F(x) __builtin_amdgcn_exp2f(x)
#else
#define EXP2F(x) exp2f(x)
#endif

namespace {

constexpr int K_GRID = 10000;          // grid points
constexpr int K_PAD  = 10240;          // 160 * 64
constexpr int DIM    = 512;            // out_features
constexpr int NBATCH = 8192;           // batch
constexpr int WPB    = 8;              // waves per block (= K-split factor)
constexpr int SPB    = 8;              // samples per block (1 per wave's dot phase)
constexpr int BLOCK  = WPB * 64;       // 512 threads
constexpr int KCHUNK = K_PAD / WPB;    // 1280 entries per wave
constexpr int NIT    = KCHUNK / 64;    // 20 float4 loads per lane
constexpr float LOG2E = 1.4426950408889634f;

// table[k] = { R_k = -(beta/2)*log2e*||yg_k||^2 , g0_k , g1_k , 0 }
// One wave per 4 grid points; W/b fragment held in registers.
__global__ __launch_bounds__(256) void build_table_kernel(
    const float* __restrict__ W, const float* __restrict__ b,
    const float* __restrict__ betta, const float* __restrict__ grid,
    float4* __restrict__ table) {
  const int lane = threadIdx.x & 63;
  const int wave = threadIdx.x >> 6;
  const int kbase = (blockIdx.x * 4 + wave) * 4;

  float w0[8], w1[8], bb[8];
  const float4* Wv = reinterpret_cast<const float4*>(W);
  #pragma unroll
  for (int j = 0; j < 4; ++j) {
    float4 wv = Wv[lane * 4 + j];
    w0[2*j]   = wv.x; w1[2*j]   = wv.y;
    w0[2*j+1] = wv.z; w1[2*j+1] = wv.w;
  }
  const float4* bv = reinterpret_cast<const float4*>(b);
  float4 b0 = bv[lane*2], b1 = bv[lane*2+1];
  bb[0]=b0.x; bb[1]=b0.y; bb[2]=b0.z; bb[3]=b0.w;
  bb[4]=b1.x; bb[5]=b1.y; bb[6]=b1.z; bb[7]=b1.w;

  const float alpha = 0.5f * betta[0] * LOG2E;
  #pragma unroll
  for (int kk = 0; kk < 4; ++kk) {
    const int k = kbase + kk;
    if (k >= K_GRID) {
      if (k < K_PAD && lane == 0) table[k] = make_float4(-1.0e30f, 0.f, 0.f, 0.f);
      continue;
    }
    const float g0 = grid[2*k], g1 = grid[2*k+1];
    float ss = 0.f;
    #pragma unroll
    for (int j = 0; j < 8; ++j) {
      float y = fmaf(g0, w0[j], fmaf(g1, w1[j], bb[j]));
      ss = fmaf(y, y, ss);
    }
    #pragma unroll
    for (int off = 32; off > 0; off >>= 1) ss += __shfl_xor(ss, off, 64);
    if (lane == 0) table[k] = make_float4(-alpha * ss, g0, g1, 0.f);
  }
}

// Block = 8 samples x 8 waves. Each wave: (a) dot for its own sample,
// (b) analytic softmax-max via concave-quadratic box max (no table pass),
// (c) single weighted-exp pass over its 1280-entry table chunk for ALL 8
//     samples, merged across waves in LDS.
__global__ __launch_bounds__(BLOCK, 6) void gtm_main_kernel(
    const float* __restrict__ X, const float* __restrict__ W,
    const float* __restrict__ b, const float* __restrict__ betta,
    const float4* __restrict__ table, float* __restrict__ out) {
  __shared__ float sACM[SPB][3];          // per-sample A, C, m
  __shared__ float sQ[6];                 // q11, q12, q22, u0, u1, r
  __shared__ float sRed[WPB][SPB][3];     // cross-wave partials

  const int lane = threadIdx.x & 63;
  const int wave = threadIdx.x >> 6;
  const int nbase = blockIdx.x * SPB;

  // --- W fragment: dims 8*lane .. 8*lane+7 ---
  float w0[8], w1[8];
  const float4* Wv = reinterpret_cast<const float4*>(W);
  #pragma unroll
  for (int j = 0; j < 4; ++j) {
    float4 wv = Wv[lane * 4 + j];
    w0[2*j]   = wv.x; w1[2*j]   = wv.y;
    w0[2*j+1] = wv.z; w1[2*j+1] = wv.w;
  }

  // --- raw dots p = (W0.x, W1.x) for this wave's sample ---
  const int n = nbase + wave;
  const float4* Xv = reinterpret_cast<const float4*>(X + (size_t)n * DIM);
  float4 xa = Xv[lane*2], xb = Xv[lane*2+1];
  float xx[8] = {xa.x, xa.y, xa.z, xa.w, xb.x, xb.y, xb.z, xb.w};
  float pa = 0.f, pc = 0.f;
  #pragma unroll
  for (int j = 0; j < 8; ++j) {
    pa = fmaf(w0[j], xx[j], pa);
    pc = fmaf(w1[j], xx[j], pc);
  }
  #pragma unroll
  for (int off = 32; off > 0; off >>= 1) {
    pa += __shfl_xor(pa, off, 64);
    pc += __shfl_xor(pc, off, 64);
  }

  // --- wave 0: Q = W^T W (2x2), u = W^T b, r = ||b||^2 ---
  if (wave == 0) {
    const float4* bv = reinterpret_cast<const float4*>(b);
    float4 b0 = bv[lane*2], b1 = bv[lane*2+1];
    float bb[8] = {b0.x, b0.y, b0.z, b0.w, b1.x, b1.y, b1.z, b1.w};
    float q11 = 0.f, q12 = 0.f, q22 = 0.f, u0 = 0.f, u1 = 0.f, rr = 0.f;
    #pragma unroll
    for (int j = 0; j < 8; ++j) {
      q11 = fmaf(w0[j], w0[j], q11);
      q12 = fmaf(w0[j], w1[j], q12);
      q22 = fmaf(w1[j], w1[j], q22);
      u0  = fmaf(w0[j], bb[j], u0);
      u1  = fmaf(w1[j], bb[j], u1);
      rr  = fmaf(bb[j], bb[j], rr);
    }
    #pragma unroll
    for (int off = 32; off > 0; off >>= 1) {
      q11 += __shfl_xor(q11, off, 64); q12 += __shfl_xor(q12, off, 64);
      q22 += __shfl_xor(q22, off, 64); u0  += __shfl_xor(u0,  off, 64);
      u1  += __shfl_xor(u1,  off, 64); rr  += __shfl_xor(rr,  off, 64);
    }
    if (lane == 0) {
      sQ[0] = q11; sQ[1] = q12; sQ[2] = q22;
      sQ[3] = u0;  sQ[4] = u1;  sQ[5] = rr;
    }
  }
  __syncthreads();

  // --- exact continuous box-max of s(g) = -alpha * f(g), f convex quadratic.
  //     Candidates: 4 clamped edge minima + interior critical point if valid.
  {
    const float q11 = sQ[0], q12 = sQ[1], q22 = sQ[2];
    const float u0 = sQ[3], u1 = sQ[4], rr = sQ[5];
    const float v0 = u0 - pa, v1 = u1 - pc;
    auto feval = [&](float a, float bq) {
      return fmaf(a, fmaf(q11, a, fmaf(2.f * q12, bq, 2.f * v0)),
                  fmaf(bq, fmaf(q22, bq, 2.f * v1), rr));
    };
    auto clamp01 = [](float t) { return fminf(fmaxf(t, 0.f), 1.f); };
    float fm = feval(0.f, clamp01(-v1 / q22));
    fm = fminf(fm, feval(1.f, clamp01(-(v1 + q12) / q22)));
    fm = fminf(fm, feval(clamp01(-v0 / q11), 0.f));
    fm = fminf(fm, feval(clamp01(-(v0 + q12) / q11), 1.f));
    const float det = fmaf(q11, q22, -q12 * q12);
    const float ga = (q12 * v1 - q22 * v0) / det;
    const float gb = (q12 * v0 - q11 * v1) / det;
    if (det > 0.f && ga >= 0.f && ga <= 1.f && gb >= 0.f && gb <= 1.f)
      fm = fminf(fm, feval(ga, gb));
    const float alpha = 0.5f * betta[0] * LOG2E;
    if (lane == 0) {
      sACM[wave][0] = 2.f * alpha * pa;   // A (base-2 logit scale)
      sACM[wave][1] = 2.f * alpha * pc;   // C
      sACM[wave][2] = -alpha * fm;        // m >= max_k s_k (slack < 0.02 bits)
    }
  }
  __syncthreads();

  float Av[SPB], Cv[SPB], Mv[SPB];
  #pragma unroll
  for (int s = 0; s < SPB; ++s) {
    Av[s] = sACM[s][0]; Cv[s] = sACM[s][1]; Mv[s] = sACM[s][2];
  }

  // --- single weighted-exp pass over this wave's K-chunk, all 8 samples ---
  float wsum[SPB], wg0[SPB], wg1[SPB];
  #pragma unroll
  for (int s = 0; s < SPB; ++s) { wsum[s] = 0.f; wg0[s] = 0.f; wg1[s] = 0.f; }

  const float4* tb = table + wave * KCHUNK + lane;
  for (int it = 0; it < NIT; it += 4) {
    float4 t0 = tb[(it + 0) * 64];
    float4 t1 = tb[(it + 1) * 64];
    float4 t2 = tb[(it + 2) * 64];
    float4 t3 = tb[(it + 3) * 64];
    #pragma unroll
    for (int s = 0; s < SPB; ++s) {
      float s0 = fmaf(t0.y, Av[s], fmaf(t0.z, Cv[s], t0.x));
      float s1 = fmaf(t1.y, Av[s], fmaf(t1.z, Cv[s], t1.x));
      float s2 = fmaf(t2.y, Av[s], fmaf(t2.z, Cv[s], t2.x));
      float s3 = fmaf(t3.y, Av[s], fmaf(t3.z, Cv[s], t3.x));
      float e0 = EXP2F(s0 - Mv[s]);
      float e1 = EXP2F(s1 - Mv[s]);
      float e2 = EXP2F(s2 - Mv[s]);
      float e3 = EXP2F(s3 - Mv[s]);
      wsum[s] += (e0 + e1) + (e2 + e3);
      wg0[s] = fmaf(e3, t3.y, fmaf(e2, t2.y, fmaf(e1, t1.y, fmaf(e0, t0.y, wg0[s]))));
      wg1[s] = fmaf(e3, t3.z, fmaf(e2, t2.z, fmaf(e1, t1.z, fmaf(e0, t0.z, wg1[s]))));
    }
  }

  // --- lane reduce, then cross-wave reduce in LDS ---
  #pragma unroll
  for (int s = 0; s < SPB; ++s) {
    float sv = wsum[s], g0 = wg0[s], g1 = wg1[s];
    #pragma unroll
    for (int off = 32; off > 0; off >>= 1) {
      sv += __shfl_xor(sv, off, 64);
      g0 += __shfl_xor(g0, off, 64);
      g1 += __shfl_xor(g1, off, 64);
    }
    if (lane == 0) {
      sRed[wave][s][0] = sv; sRed[wave][s][1] = g0; sRed[wave][s][2] = g1;
    }
  }
  __syncthreads();

  if (wave == 0) {
    const int s = lane >> 3, w = lane & 7;
    float sv = sRed[w][s][0], g0 = sRed[w][s][1], g1 = sRed[w][s][2];
    #pragma unroll
    for (int off = 1; off < 8; off <<= 1) {
      sv += __shfl_xor(sv, off, 64);
      g0 += __shfl_xor(g0, off, 64);
      g1 += __shfl_xor(g1, off, 64);
    }
    if (w == 0) {
      float inv = 1.f / sv;
      reinterpret_cast<float2*>(out)[nbase + s] = make_float2(g0 * inv, g1 * inv);
    }
  }
}

}  // namespace

extern "C" void kernel_launch(void* const* d_in, const int* in_sizes, int n_in,
                              void* d_out, int out_size, void* d_ws, size_t ws_size,
                              hipStream_t stream) {
  const float* X     = (const float*)d_in[0];  // [8192, 512]
  const float* W     = (const float*)d_in[1];  // [512, 2]
  const float* b     = (const float*)d_in[2];  // [512]
  const float* betta = (const float*)d_in[3];  // [1]
  const float* grid  = (const float*)d_in[4];  // [10000, 2]
  float* out = (float*)d_out;                  // [8192, 2]
  float4* table = (float4*)d_ws;               // 160 KiB

  build_table_kernel<<<K_PAD / 16, 256, 0, stream>>>(W, b, betta, grid, table);

  const int blocks = NBATCH / SPB;             // 1024
  gtm_main_kernel<<<blocks, BLOCK, 0, stream>>>(X, W, b, betta, table, out);
}